// Round 2
// baseline (496.844 us; speedup 1.0000x reference)
//
#include <hip/hip_runtime.h>
#include <hip/hip_fp16.h>
#include <stdint.h>

// Fused MHA forward, MI355X gfx950.
// B=4 S=2048 E=1024 H=16 D=64. All MFMA in f16 (fp32 accum) for accuracy.

typedef _Float16 f16;
typedef _Float16 f16x8 __attribute__((ext_vector_type(8)));
typedef _Float16 f16x4 __attribute__((ext_vector_type(4)));
typedef float f32x4 __attribute__((ext_vector_type(4)));

#define DEVI static __device__ __forceinline__

// async global->LDS, 16B per lane. LDS dest is wave-uniform base + lane*16.
DEVI void gload16(void* lds, const void* g) {
    __builtin_amdgcn_global_load_lds(
        (const __attribute__((address_space(1))) uint32_t*)g,
        (__attribute__((address_space(3))) uint32_t*)lds, 16, 0, 0);
}

// ---------------------------------------------------------------- cast f32->f16
__global__ __launch_bounds__(256) void cast_kernel(const float* __restrict__ in,
                                                   f16* __restrict__ out, int n4) {
    int i = blockIdx.x * 256 + threadIdx.x;
    if (i < n4) {
        float4 v = ((const float4*)in)[i];
        f16x4 h;
        h[0] = (f16)v.x; h[1] = (f16)v.y; h[2] = (f16)v.z; h[3] = (f16)v.w;
        ((f16x4*)out)[i] = h;
    }
}

// ---------------------------------------------------------------- GEMM  C = A @ B^T
// A: [M][K] row-major f16.  B: [N][K] row-major f16 (i.e. torch Linear weight).
// FINAL=0: write f16 Ch.  FINAL=1: write f32 Cf + bias.
// 128x128 tile, BK=64, 256 threads (4 waves, 2x2), mfma_f32_16x16x32_f16.
template <int FINAL>
__global__ __launch_bounds__(256) void gemm_bt(const f16* __restrict__ A,
                                               const f16* __restrict__ B,
                                               f16* __restrict__ Ch,
                                               float* __restrict__ Cf,
                                               const float* __restrict__ bias,
                                               int M, int N, int K) {
    __shared__ f16 As[128][64];
    __shared__ f16 Bs[128][64];
    const int tid  = threadIdx.x;
    const int w    = tid >> 6, lane = tid & 63;
    const int wr   = w >> 1,  wc   = w & 1;
    const int m0   = blockIdx.y * 128, n0 = blockIdx.x * 128;
    const int lrw  = lane >> 3;   // staging: row within 8-row group
    const int lsl  = lane & 7;    // staging: 16B slot within row
    const int frow = lane & 15;   // fragment row/col index
    const int fgrp = lane >> 4;   // fragment k-group

    f32x4 acc[4][4] = {};

    for (int kt = 0; kt < K; kt += 64) {
        __syncthreads();
        // stage A-tile and B-tile: linear LDS dest, XOR-swizzled global source
        // (LDS[r][s] holds global k-slot s^(r&7); reads undo the same XOR)
#pragma unroll
        for (int t = 0; t < 4; ++t) {
            int rb = (w * 4 + t) * 8;
            int r  = rb + lrw;
            gload16(&As[rb][0], A + (size_t)(m0 + r) * K + kt + ((lsl ^ (r & 7)) * 8));
            gload16(&Bs[rb][0], B + (size_t)(n0 + r) * K + kt + ((lsl ^ (r & 7)) * 8));
        }
        __syncthreads();
#pragma unroll
        for (int kk = 0; kk < 2; ++kk) {
            const int slot = kk * 4 + fgrp;
            f16x8 af[4], bf[4];
#pragma unroll
            for (int i = 0; i < 4; ++i) {
                int r = wr * 64 + i * 16 + frow;
                af[i] = *(const f16x8*)&As[r][(slot ^ (r & 7)) * 8];
            }
#pragma unroll
            for (int j = 0; j < 4; ++j) {
                int r = wc * 64 + j * 16 + frow;
                bf[j] = *(const f16x8*)&Bs[r][(slot ^ (r & 7)) * 8];
            }
#pragma unroll
            for (int i = 0; i < 4; ++i)
#pragma unroll
                for (int j = 0; j < 4; ++j)
                    acc[i][j] = __builtin_amdgcn_mfma_f32_16x16x32_f16(af[i], bf[j], acc[i][j], 0, 0, 0);
        }
    }
    // epilogue: C/D layout col=lane&15, row=(lane>>4)*4+reg
#pragma unroll
    for (int i = 0; i < 4; ++i)
#pragma unroll
        for (int j = 0; j < 4; ++j)
#pragma unroll
            for (int rg = 0; rg < 4; ++rg) {
                int r = m0 + wr * 64 + i * 16 + fgrp * 4 + rg;
                int c = n0 + wc * 64 + j * 16 + frow;
                float v = acc[i][j][rg];
                if (FINAL)
                    Cf[(size_t)r * N + c] = v + bias[c];
                else
                    Ch[(size_t)r * N + c] = (f16)v;
            }
}

// ---------------------------------------------------------------- flash attention
// One block = 128 q-rows of one (b,h). 4 waves x 32 rows. K/V tiles of 64.
__global__ __launch_bounds__(256) void attn_kernel(const f16* __restrict__ Q,
                                                   const f16* __restrict__ K,
                                                   const f16* __restrict__ V,
                                                   f16* __restrict__ O) {
    constexpr int S = 2048, E = 1024, D = 64;
    __shared__ f16 Qs[128][64];
    __shared__ f16 Ks[64][64];
    __shared__ f16 Vt[64][64];      // transposed: Vt[d][kj]
    __shared__ f16 Ps[4][32][64];   // per-wave P staging

    const int tid  = threadIdx.x;
    const int w    = tid >> 6, lane = tid & 63;
    const int bh   = blockIdx.y;               // 0..63
    const int b    = bh >> 4, h = bh & 15;
    const int q0   = blockIdx.x * 128;
    const int lrw  = lane >> 3, lsl = lane & 7;
    const int frow = lane & 15, fgrp = lane >> 4;

    const size_t base = (size_t)b * S * E + (size_t)h * D;
    const f16* Qp = Q + base;
    const f16* Kp = K + base;
    const f16* Vp = V + base;

    // stage Q-tile once
#pragma unroll
    for (int t = 0; t < 4; ++t) {
        int rb = (w * 4 + t) * 8;
        int r  = rb + lrw;
        gload16(&Qs[rb][0], Qp + (size_t)(q0 + r) * E + ((lsl ^ (r & 7)) * 8));
    }
    __syncthreads();

    // hoist Q fragments to registers (fixed per wave for the whole K loop)
    f16x8 qa[2][2];
#pragma unroll
    for (int i = 0; i < 2; ++i)
#pragma unroll
        for (int kk = 0; kk < 2; ++kk) {
            int r = w * 32 + i * 16 + frow;
            int slot = kk * 4 + fgrp;
            qa[i][kk] = *(const f16x8*)&Qs[r][(slot ^ (r & 7)) * 8];
        }

    float rm[2][4], rl[2][4];
    f32x4 o[2][4] = {};
#pragma unroll
    for (int i = 0; i < 2; ++i)
#pragma unroll
        for (int rg = 0; rg < 4; ++rg) { rm[i][rg] = -1e30f; rl[i][rg] = 0.f; }

    const int kjp = tid >> 3;          // V transpose staging: kj pair 0..31
    const int vd0 = (tid & 7) * 8;     // d group

    for (int kt = 0; kt < S; kt += 64) {
        __syncthreads();  // protect Ks/Vt from previous iteration's readers
        // stage K-tile (64 rows): async direct-to-LDS
#pragma unroll
        for (int t = 0; t < 2; ++t) {
            int rb = (w * 2 + t) * 8;
            int r  = rb + lrw;
            gload16(&Ks[rb][0], Kp + (size_t)(kt + r) * E + ((lsl ^ (r & 7)) * 8));
        }
        // stage V transposed: read 2 rows x 8 d, write packed u32 pairs
        {
            int kj = kjp * 2;
            f16x8 va = *(const f16x8*)(Vp + (size_t)(kt + kj) * E + vd0);
            f16x8 vb = *(const f16x8*)(Vp + (size_t)(kt + kj + 1) * E + vd0);
#pragma unroll
            for (int u = 0; u < 8; ++u) {
                int d = vd0 + u;
                union { f16 hh[2]; uint32_t u32; } pk;
                pk.hh[0] = va[u]; pk.hh[1] = vb[u];
                char* bp = (char*)Vt + d * 128 + (((kj >> 3) ^ (d & 7)) * 16) + (kj & 7) * 2;
                *(uint32_t*)bp = pk.u32;
            }
        }
        __syncthreads();

        // scores: s[q][kj] = sum_d Q[q][d] K[kj][d]
        f32x4 s[2][4] = {};
#pragma unroll
        for (int kk = 0; kk < 2; ++kk) {
            const int slot = kk * 4 + fgrp;
            f16x8 kb[4];
#pragma unroll
            for (int j = 0; j < 4; ++j) {
                int r = j * 16 + frow;
                kb[j] = *(const f16x8*)&Ks[r][(slot ^ (r & 7)) * 8];
            }
#pragma unroll
            for (int i = 0; i < 2; ++i)
#pragma unroll
                for (int j = 0; j < 4; ++j)
                    s[i][j] = __builtin_amdgcn_mfma_f32_16x16x32_f16(qa[i][kk], kb[j], s[i][j], 0, 0, 0);
        }

        // online softmax (scale 1/8), rows live in (i, reg) across the 16-lane group
#pragma unroll
        for (int i = 0; i < 2; ++i)
#pragma unroll
            for (int rg = 0; rg < 4; ++rg) {
                float v0 = fmaxf(fmaxf(s[i][0][rg], s[i][1][rg]),
                                 fmaxf(s[i][2][rg], s[i][3][rg]));
#pragma unroll
                for (int msk = 1; msk < 16; msk <<= 1)
                    v0 = fmaxf(v0, __shfl_xor(v0, msk));
                v0 *= 0.125f;
                float mnew  = fmaxf(rm[i][rg], v0);
                float scale = exp2f((rm[i][rg] - mnew) * 1.44269504f);
                float rsum  = 0.f;
#pragma unroll
                for (int j = 0; j < 4; ++j) {
                    float p = exp2f((s[i][j][rg] * 0.125f - mnew) * 1.44269504f);
                    s[i][j][rg] = p;
                    rsum += p;
                }
#pragma unroll
                for (int msk = 1; msk < 16; msk <<= 1)
                    rsum += __shfl_xor(rsum, msk);
                rl[i][rg] = rl[i][rg] * scale + rsum;
                rm[i][rg] = mnew;
#pragma unroll
                for (int jd = 0; jd < 4; ++jd) o[i][jd][rg] *= scale;
            }

        // write P (f16) to per-wave LDS in A-fragment-readable layout
#pragma unroll
        for (int i = 0; i < 2; ++i)
#pragma unroll
            for (int j = 0; j < 4; ++j)
#pragma unroll
                for (int rg = 0; rg < 4; ++rg) {
                    int pr = i * 16 + fgrp * 4 + rg;
                    int pc = j * 16 + frow;
                    char* bp = (char*)&Ps[w][0][0] + pr * 128 +
                               (((pc >> 3) ^ (pr & 7)) * 16) + (pc & 7) * 2;
                    *(f16*)bp = (f16)s[i][j][rg];
                }
        asm volatile("s_waitcnt lgkmcnt(0)" ::: "memory");

        // PV: o[q][d] += P[q][kj] V[kj][d]
#pragma unroll
        for (int kk = 0; kk < 2; ++kk) {
            const int slot = kk * 4 + fgrp;
            f16x8 pa[2], vb[4];
#pragma unroll
            for (int i = 0; i < 2; ++i) {
                int r = i * 16 + frow;
                pa[i] = *(const f16x8*)((char*)&Ps[w][0][0] + r * 128 + ((slot ^ (r & 7)) * 16));
            }
#pragma unroll
            for (int jd = 0; jd < 4; ++jd) {
                int d = jd * 16 + frow;
                vb[jd] = *(const f16x8*)((char*)Vt + d * 128 + ((slot ^ (d & 7)) * 16));
            }
#pragma unroll
            for (int i = 0; i < 2; ++i)
#pragma unroll
                for (int jd = 0; jd < 4; ++jd)
                    o[i][jd] = __builtin_amdgcn_mfma_f32_16x16x32_f16(pa[i], vb[jd], o[i][jd], 0, 0, 0);
        }
    }

    // normalize and store ctx (f16), layout [B,S,E] with head offset
#pragma unroll
    for (int i = 0; i < 2; ++i)
#pragma unroll
        for (int rg = 0; rg < 4; ++rg) {
            float inv = 1.f / rl[i][rg];
            int r = q0 + w * 32 + i * 16 + fgrp * 4 + rg;
#pragma unroll
            for (int jd = 0; jd < 4; ++jd) {
                int d = jd * 16 + frow;
                O[base + (size_t)r * E + d] = (f16)(o[i][jd][rg] * inv);
            }
        }
}

// ---------------------------------------------------------------- launch
extern "C" void kernel_launch(void* const* d_in, const int* in_sizes, int n_in,
                              void* d_out, int out_size, void* d_ws, size_t ws_size,
                              hipStream_t stream) {
    const int B = 4, S = 2048, E = 1024;
    const int M = B * S;  // 8192

    const float* x  = (const float*)d_in[0];
    const float* Wq = (const float*)d_in[1];
    const float* Wk = (const float*)d_in[2];
    const float* Wv = (const float*)d_in[3];
    const float* Wo = (const float*)d_in[4];
    const float* bo = (const float*)d_in[5];

    char* ws = (char*)d_ws;
    size_t off = 0;
    f16* xh  = (f16*)(ws + off); off += (size_t)M * E * sizeof(f16);
    f16* Qh  = (f16*)(ws + off); off += (size_t)M * E * sizeof(f16);
    f16* Kh  = (f16*)(ws + off); off += (size_t)M * E * sizeof(f16);
    f16* Vh  = (f16*)(ws + off); off += (size_t)M * E * sizeof(f16);
    f16* Wqh = (f16*)(ws + off); off += (size_t)E * E * sizeof(f16);
    f16* Wkh = (f16*)(ws + off); off += (size_t)E * E * sizeof(f16);
    f16* Wvh = (f16*)(ws + off); off += (size_t)E * E * sizeof(f16);
    f16* Woh = (f16*)(ws + off); off += (size_t)E * E * sizeof(f16);
    f16* ctxh = xh;  // x is dead after the V projection; reuse its slot

    // casts
    {
        int n4 = M * E / 4;
        cast_kernel<<<(n4 + 255) / 256, 256, 0, stream>>>(x, xh, n4);
        int w4 = E * E / 4;
        cast_kernel<<<(w4 + 255) / 256, 256, 0, stream>>>(Wq, Wqh, w4);
        cast_kernel<<<(w4 + 255) / 256, 256, 0, stream>>>(Wk, Wkh, w4);
        cast_kernel<<<(w4 + 255) / 256, 256, 0, stream>>>(Wv, Wvh, w4);
        cast_kernel<<<(w4 + 255) / 256, 256, 0, stream>>>(Wo, Woh, w4);
    }

    dim3 ggrid(E / 128, M / 128);  // (8, 64)
    gemm_bt<0><<<ggrid, 256, 0, stream>>>(xh, Wqh, Qh, nullptr, nullptr, M, E, E);
    gemm_bt<0><<<ggrid, 256, 0, stream>>>(xh, Wkh, Kh, nullptr, nullptr, M, E, E);
    gemm_bt<0><<<ggrid, 256, 0, stream>>>(xh, Wvh, Vh, nullptr, nullptr, M, E, E);

    attn_kernel<<<dim3(S / 128, B * 16), 256, 0, stream>>>(Qh, Kh, Vh, ctxh);

    gemm_bt<1><<<ggrid, 256, 0, stream>>>(ctxh, Woh, nullptr, (float*)d_out, bo, M, E, E);
}